// Round 18
// baseline (37.285 us; speedup 1.0000x reference)
//
#include <hip/hip_runtime.h>
#include <hip/hip_bf16.h>

#define B_SZ 4096
#define F_N  39
#define V_N  100000
#define D_N  16
#define H_N  400
#define K1   624      // F*D
#define K1P  640      // K1 padded to mult of 64
#define NP2  448      // H padded to mult of 64 (7 tiles)

typedef __attribute__((ext_vector_type(8))) short short8;
typedef __attribute__((ext_vector_type(4))) float f32x4;

typedef const __attribute__((address_space(1))) void g_void;
typedef __attribute__((address_space(3))) void l_void;

#define W1_TILES 70          // (K1P/64) x (NP2/64)
#define W2_TILES 49          // 7 x 7
#define T_TILES  (W1_TILES + W2_TILES)   // 119, dispatched first
#define GB       1024        // gather blocks, 4 rows each
#define PREP_GRID (T_TILES + 1 + GB)

// ---- kernel 1: weight prep (first) + gather + register-only FM (r17) -------
__global__ __launch_bounds__(256) void prep_kernel(
    const int*   __restrict__ Xi,
    const float* __restrict__ Xv,
    const float* __restrict__ fst_t,
    const float* __restrict__ sec_t,
    const float* __restrict__ bias,
    const float* __restrict__ W1, const float* __restrict__ b1,
    const float* __restrict__ W2, const float* __restrict__ b2,
    __hip_bfloat16* __restrict__ sec_flat,
    __hip_bfloat16* __restrict__ W1t, __hip_bfloat16* __restrict__ W2t,
    float* __restrict__ b1p, float* __restrict__ b2p,
    float* __restrict__ out)
{
    const int bid = blockIdx.x;
    const int tid = threadIdx.x;

    __shared__ __align__(16) float ttile[64 * 65];   // transpose branch only

    if (bid < T_TILES) {
        const float* Wsrc; __hip_bfloat16* Wdst;
        int Ksrc, Kdst, kb, nb2, tb = bid;
        if (tb < W1_TILES) { Wsrc = W1; Wdst = W1t; Ksrc = K1;  Kdst = K1P; kb = tb / 7; nb2 = tb % 7; }
        else { tb -= W1_TILES; Wsrc = W2; Wdst = W2t; Ksrc = H_N; Kdst = NP2; kb = tb / 7; nb2 = tb % 7; }
        const int k0 = kb * 64, n0 = nb2 * 64;
        #pragma unroll
        for (int p = 0; p < 4; ++p) {
            const int r  = (tid >> 4) + p * 16;   // src row (k)
            const int c4 = (tid & 15) * 4;        // src col (n)
            const int gk = k0 + r, gn = n0 + c4;
            float4 v = make_float4(0.f, 0.f, 0.f, 0.f);
            if (gk < Ksrc && gn + 3 < H_N)
                v = *(const float4*)(Wsrc + (size_t)gk * H_N + gn);
            ttile[(c4 + 0) * 65 + r] = v.x;
            ttile[(c4 + 1) * 65 + r] = v.y;
            ttile[(c4 + 2) * 65 + r] = v.z;
            ttile[(c4 + 3) * 65 + r] = v.w;
        }
        __syncthreads();
        const int rr = tid >> 2, cc = (tid & 3) * 16;
        const int n  = n0 + rr;
        short8 s0, s1;
        #pragma unroll
        for (int j = 0; j < 8; ++j) {
            s0[j] = (short)__bfloat16_as_ushort(__float2bfloat16(ttile[rr * 65 + cc + j]));
            s1[j] = (short)__bfloat16_as_ushort(__float2bfloat16(ttile[rr * 65 + cc + 8 + j]));
        }
        const int c0  = (k0 + cc) >> 3;
        const int c1  = c0 + 1;
        const int c0s = (c0 & ~7) | ((c0 ^ n) & 7);
        const int c1s = (c1 & ~7) | ((c1 ^ n) & 7);
        *(short8*)(Wdst + (size_t)n * Kdst + c0s * 8) = s0;
        *(short8*)(Wdst + (size_t)n * Kdst + c1s * 8) = s1;
        return;
    }

    if (bid == T_TILES) {
        if (tid < 256) {
            b1p[tid] = (tid < H_N) ? b1[tid] : 0.f;
            b2p[tid] = (tid < H_N) ? b2[tid] : 0.f;
            if (tid + 256 < NP2) {
                b1p[tid + 256] = (tid + 256 < H_N) ? b1[tid + 256] : 0.f;
                b2p[tid + 256] = (tid + 256 < H_N) ? b2[tid + 256] : 0.f;
            }
        }
        return;
    }

    // ----- gather branch: 4 rows, 1 wave per row, register-only FM ----------
    const int gb   = bid - (T_TILES + 1);
    const int r    = tid >> 6;                // row 0..3 (= wave id)
    const int l    = tid & 63;
    const int base = gb * (4 * F_N) + r * F_N;
    const int grow = gb * 4 + r;

    int   idxv[4];
    float valv[4];
    #pragma unroll
    for (int it = 0; it < 4; ++it) {
        const int t  = l + it * 64;
        const int fi = (t < 156) ? (t >> 2) : ((t < 156 + F_N) ? (t - 156) : 0);
        idxv[it] = Xi[base + fi];
        valv[it] = Xv[base + fi];
    }

    float4 gv[4];
    float  fv[4];
    #pragma unroll
    for (int it = 0; it < 4; ++it) {
        const int t = l + it * 64;
        gv[it] = make_float4(0.f, 0.f, 0.f, 0.f);
        fv[it] = 0.f;
        if (t < 156) {
            gv[it] = *(const float4*)(sec_t +
                     ((long long)(t >> 2) * V_N + idxv[it]) * D_N + (t & 3) * 4);
        } else if (t < 156 + F_N) {
            fv[it] = fst_t[(long long)(t - 156) * V_N + idxv[it]];
        }
    }

    float4 vsum = make_float4(0.f, 0.f, 0.f, 0.f);  // colsum partial (d-class l&3)
    float  ssq = 0.f, fstp = 0.f;
    #pragma unroll
    for (int it = 0; it < 4; ++it) {
        const int t = l + it * 64;
        if (t < 160) {
            float4 v = make_float4(0.f, 0.f, 0.f, 0.f);
            if (t < 156) {
                const float val = valv[it];
                v.x = gv[it].x * val; v.y = gv[it].y * val;
                v.z = gv[it].z * val; v.w = gv[it].w * val;
                ssq += v.x * v.x + v.y * v.y + v.z * v.z + v.w * v.w;
                vsum.x += v.x; vsum.y += v.y; vsum.z += v.z; vsum.w += v.w;
            }
            ushort4 pk;
            pk.x = __bfloat16_as_ushort(__float2bfloat16(v.x));
            pk.y = __bfloat16_as_ushort(__float2bfloat16(v.y));
            pk.z = __bfloat16_as_ushort(__float2bfloat16(v.z));
            pk.w = __bfloat16_as_ushort(__float2bfloat16(v.w));
            const int ch = t >> 1;                       // 16B chunk
            const int cs = (ch & ~7) | ((ch ^ grow) & 7);
            *(ushort4*)(sec_flat + (size_t)grow * K1P + cs * 8 + (t & 1) * 4) = pk;
        }
        if (t >= 156 && t < 156 + F_N)
            fstp += fv[it] * valv[it];
    }

    #pragma unroll
    for (int off = 4; off < 64; off <<= 1) {
        vsum.x += __shfl_xor(vsum.x, off, 64);
        vsum.y += __shfl_xor(vsum.y, off, 64);
        vsum.z += __shfl_xor(vsum.z, off, 64);
        vsum.w += __shfl_xor(vsum.w, off, 64);
    }
    float s2 = vsum.x * vsum.x + vsum.y * vsum.y + vsum.z * vsum.z + vsum.w * vsum.w;
    s2 += __shfl_xor(s2, 1, 64);
    s2 += __shfl_xor(s2, 2, 64);
    float rsc = fstp - 0.5f * ssq;
    #pragma unroll
    for (int off = 1; off < 64; off <<= 1)
        rsc += __shfl_xor(rsc, off, 64);
    if (l == 0) out[grow] = rsc + 0.5f * s2 + bias[0];
}

// counted-vmcnt wait (immediate operand required)
__device__ __forceinline__ void waitv(int n) {
    if      (n <= 0)  asm volatile("s_waitcnt vmcnt(0)"  ::: "memory");
    else if (n == 4)  asm volatile("s_waitcnt vmcnt(4)"  ::: "memory");
    else if (n == 8)  asm volatile("s_waitcnt vmcnt(8)"  ::: "memory");
    else if (n == 12) asm volatile("s_waitcnt vmcnt(12)" ::: "memory");
    else if (n == 16) asm volatile("s_waitcnt vmcnt(16)" ::: "memory");
    else              asm volatile("s_waitcnt vmcnt(20)" ::: "memory");
}

// ---- kernel 2/3: bf16 MFMA GEMM, 64x64 tile, DEPTH=6 pipeline --------------
// prefetch distance 5 phases (~500-600 cyc) to cover the L3-hit latency of
// cold cross-XCD A/B reads (sec_flat / h / W written by other XCDs' blocks).
template <int KT, bool ROWSUM>
__global__ __launch_bounds__(256) void mfma_gemm(
    const __hip_bfloat16* __restrict__ A,
    const __hip_bfloat16* __restrict__ Bt,
    const float* __restrict__ bias,
    __hip_bfloat16* __restrict__ C,
    float* __restrict__ out)
{
    constexpr int DEPTH = 6;
    __shared__ __align__(16) __hip_bfloat16 As[DEPTH][64 * 64];  // 48 KB
    __shared__ __align__(16) __hip_bfloat16 Bs[DEPTH][64 * 64];  // 48 KB

    const int tid  = threadIdx.x;
    const int lane = tid & 63;
    const int wid  = tid >> 6;       // 4 waves: 2 (M) x 2 (N)
    const int wm   = wid >> 1;
    const int wn   = wid & 1;
    const int lr   = lane & 15;
    const int lg4  = lane >> 4;

    // XCD-chunked swizzle: 56 consecutive tiles per XCD (8 row-panels)
    const int lin  = blockIdx.x;
    const int swz  = (lin & 7) * 56 + (lin >> 3);
    const int row0 = (swz / 7) * 64;
    const int col0 = (swz % 7) * 64;

    const int sr = tid >> 3;         // staging row 0..31
    const int sc = (tid & 7) * 8;    // 16B chunk

    auto STAGE = [&](int buf, int k0) {   // 4 gload_lds per thread
        #pragma unroll
        for (int i = 0; i < 2; ++i) {
            __builtin_amdgcn_global_load_lds(
                (g_void*)(A + (size_t)(row0 + i * 32 + sr) * KT + k0 + sc),
                (l_void*)(&As[buf][(i * 32 + sr) * 64 + sc]), 16, 0, 0);
            __builtin_amdgcn_global_load_lds(
                (g_void*)(Bt + (size_t)(col0 + i * 32 + sr) * KT + k0 + sc),
                (l_void*)(&Bs[buf][(i * 32 + sr) * 64 + sc]), 16, 0, 0);
        }
    };

    constexpr int NT = KT / 64;                       // 10 or 7
    constexpr int P0 = (NT < DEPTH) ? NT : DEPTH;     // prologue stages
    #pragma unroll
    for (int s = 0; s < P0; ++s) STAGE(s, s * 64);

    f32x4 acc[2][2] = {};
    #pragma unroll
    for (int t = 0; t < NT; ++t) {
        // issued count at this wait (constant-folds under full unroll):
        // prologue P0 + one per phase 1..t-1 while stages remain
        const int extra = (t >= 1) ? ((t - 1 < NT - P0) ? (t - 1) : (NT - P0)) : 0;
        const int ia    = P0 + extra;
        waitv(4 * (ia - t - 1));     // stage t landed; never drains mid-loop
        __builtin_amdgcn_s_barrier();
        // issue next stage (index ia) if room and remaining
        if (ia < NT && ia - t < DEPTH)
            STAGE(ia % DEPTH, ia * 64);

        const int cb = t % DEPTH;
        #pragma unroll
        for (int ks = 0; ks < 2; ++ks) {
            short8 a[2], bb[2];
            #pragma unroll
            for (int m = 0; m < 2; ++m) {
                const int row = wm * 32 + m * 16 + lr;
                const int ch  = (ks * 4 + lg4) ^ (row & 7);
                a[m] = *(const short8*)(&As[cb][row * 64 + ch * 8]);
            }
            #pragma unroll
            for (int n = 0; n < 2; ++n) {
                const int row = wn * 32 + n * 16 + lr;
                const int ch  = (ks * 4 + lg4) ^ (row & 7);
                bb[n] = *(const short8*)(&Bs[cb][row * 64 + ch * 8]);
            }
            #pragma unroll
            for (int m = 0; m < 2; ++m)
                #pragma unroll
                for (int n = 0; n < 2; ++n)
                    acc[m][n] = __builtin_amdgcn_mfma_f32_16x16x32_bf16(
                        a[m], bb[n], acc[m][n], 0, 0, 0);
        }
    }

    // bias loaded here (deferred): vmcnt ledger in the loop stayed pure
    float bvv[2];
    #pragma unroll
    for (int n = 0; n < 2; ++n)
        bvv[n] = bias[col0 + wn * 32 + n * 16 + lr];

    // epilogue — C/D layout: col = lane&15, row = (lane>>4)*4 + reg  [m89]
    if constexpr (!ROWSUM) {
        __syncthreads();
        float* ctile = (float*)&As[0][0];      // 64x64 f32 = 16 KB (As[0..1])
        #pragma unroll
        for (int m = 0; m < 2; ++m) {
            const int rb = wm * 32 + m * 16 + lg4 * 4;
            #pragma unroll
            for (int n = 0; n < 2; ++n) {
                const int col = wn * 32 + n * 16 + lr;
                #pragma unroll
                for (int r = 0; r < 4; ++r)
                    ctile[(rb + r) * 64 + col] = fmaxf(acc[m][n][r] + bvv[n], 0.f);
            }
        }
        __syncthreads();
        const int row = tid >> 2;              // 0..63
        const int cc  = (tid & 3) * 16;
        short8 s0, s1;
        #pragma unroll
        for (int j = 0; j < 8; ++j) {
            s0[j] = (short)__bfloat16_as_ushort(__float2bfloat16(ctile[row * 64 + cc + j]));
            s1[j] = (short)__bfloat16_as_ushort(__float2bfloat16(ctile[row * 64 + cc + 8 + j]));
        }
        const int c0  = (col0 + cc) >> 3;
        const int c1  = c0 + 1;
        const int c0s = (c0 & ~7) | ((c0 ^ row) & 7);
        const int c1s = (c1 & ~7) | ((c1 ^ row) & 7);
        *(short8*)(C + (size_t)(row0 + row) * NP2 + c0s * 8) = s0;
        *(short8*)(C + (size_t)(row0 + row) * NP2 + c1s * 8) = s1;
    } else {
        #pragma unroll
        for (int m = 0; m < 2; ++m) {
            float v[4] = {0.f, 0.f, 0.f, 0.f};
            #pragma unroll
            for (int n = 0; n < 2; ++n) {
                #pragma unroll
                for (int r = 0; r < 4; ++r)
                    v[r] += fmaxf(acc[m][n][r] + bvv[n], 0.f);
            }
            #pragma unroll
            for (int off = 1; off < 16; off <<= 1)
                #pragma unroll
                for (int r = 0; r < 4; ++r)
                    v[r] += __shfl_xor(v[r], off, 64);
            if (lr == 0) {
                const int row = row0 + wm * 32 + m * 16 + lg4 * 4;
                #pragma unroll
                for (int r = 0; r < 4; ++r)
                    atomicAdd(out + row + r, v[r]);
            }
        }
    }
}

extern "C" void kernel_launch(void* const* d_in, const int* in_sizes, int n_in,
                              void* d_out, int out_size, void* d_ws, size_t ws_size,
                              hipStream_t stream)
{
    const int*   Xi    = (const int*)  d_in[0];
    const float* Xv    = (const float*)d_in[1];
    const float* fst_t = (const float*)d_in[2];
    const float* sec_t = (const float*)d_in[3];
    const float* W1    = (const float*)d_in[4];
    const float* b1    = (const float*)d_in[5];
    const float* W2    = (const float*)d_in[6];
    const float* b2    = (const float*)d_in[7];
    const float* bias  = (const float*)d_in[8];

    float* out = (float*)d_out;
    char*  wsb = (char*)d_ws;

    __hip_bfloat16* sec_flat = (__hip_bfloat16*)(wsb);                // 4096*640*2
    __hip_bfloat16* h        = (__hip_bfloat16*)(wsb + 5242880);      // 4096*448*2
    __hip_bfloat16* W1t      = (__hip_bfloat16*)(wsb + 8912896);      // 448*640*2
    __hip_bfloat16* W2t      = (__hip_bfloat16*)(wsb + 9486336);      // 448*448*2
    float*          b1p      = (float*)(wsb + 9887744);               // 448*4
    float*          b2p      = (float*)(wsb + 9889536);               // 448*4

    prep_kernel<<<PREP_GRID, 256, 0, stream>>>(
        Xi, Xv, fst_t, sec_t, bias, W1, b1, W2, b2,
        sec_flat, W1t, W2t, b1p, b2p, out);

    mfma_gemm<K1P, false><<<448, 256, 0, stream>>>(sec_flat, W1t, b1p, h, nullptr);
    mfma_gemm<NP2, true ><<<448, 256, 0, stream>>>(h, W2t, b2p, nullptr, out);
}

// Round 19
// 31.144 us; speedup vs baseline: 1.1972x; 1.1972x over previous
//
#include <hip/hip_runtime.h>
#include <hip/hip_bf16.h>

#define B_SZ 4096
#define F_N  39
#define V_N  100000
#define D_N  16
#define H_N  400
#define K1   624      // F*D
#define K1P  640      // K1 padded to mult of 64
#define NP2  448      // H padded to mult of 64 (7 tiles)

typedef __attribute__((ext_vector_type(8))) short short8;
typedef __attribute__((ext_vector_type(4))) float f32x4;

typedef const __attribute__((address_space(1))) void g_void;
typedef __attribute__((address_space(3))) void l_void;

#define W1_TILES 70          // (K1P/64) x (NP2/64)
#define W2_TILES 49          // 7 x 7
#define T_TILES  (W1_TILES + W2_TILES)   // 119, dispatched first
#define GB       1024        // gather blocks, 4 rows each
#define PREP_GRID (T_TILES + 1 + GB)     // 120 + 1024; 120 % 8 == 0

// ---- kernel 1: weight prep + gather (XCD-aligned rows) + register FM -------
// Gather block gb runs on XCD (gb&7); it writes sec_flat rows
// (gb&7)*512 + (gb>>3)*4 .. +3  -> XCD x produces exactly rows 512x..512x+511,
// the same panel GEMM1's XCD-x blocks consume => A reads are L2-local.
__global__ __launch_bounds__(256) void prep_kernel(
    const int*   __restrict__ Xi,
    const float* __restrict__ Xv,
    const float* __restrict__ fst_t,
    const float* __restrict__ sec_t,
    const float* __restrict__ bias,
    const float* __restrict__ W1, const float* __restrict__ b1,
    const float* __restrict__ W2, const float* __restrict__ b2,
    __hip_bfloat16* __restrict__ sec_flat,
    __hip_bfloat16* __restrict__ W1t, __hip_bfloat16* __restrict__ W2t,
    float* __restrict__ b1p, float* __restrict__ b2p,
    float* __restrict__ out)
{
    const int bid = blockIdx.x;
    const int tid = threadIdx.x;

    __shared__ __align__(16) float ttile[64 * 65];   // transpose branch only

    if (bid < T_TILES) {
        // ---------------- weight transpose branch (pre-swizzled dst) --------
        const float* Wsrc; __hip_bfloat16* Wdst;
        int Ksrc, Kdst, kb, nb2, tb = bid;
        if (tb < W1_TILES) { Wsrc = W1; Wdst = W1t; Ksrc = K1;  Kdst = K1P; kb = tb / 7; nb2 = tb % 7; }
        else { tb -= W1_TILES; Wsrc = W2; Wdst = W2t; Ksrc = H_N; Kdst = NP2; kb = tb / 7; nb2 = tb % 7; }
        const int k0 = kb * 64, n0 = nb2 * 64;
        #pragma unroll
        for (int p = 0; p < 4; ++p) {
            const int r  = (tid >> 4) + p * 16;   // src row (k)
            const int c4 = (tid & 15) * 4;        // src col (n)
            const int gk = k0 + r, gn = n0 + c4;
            float4 v = make_float4(0.f, 0.f, 0.f, 0.f);
            if (gk < Ksrc && gn + 3 < H_N)
                v = *(const float4*)(Wsrc + (size_t)gk * H_N + gn);
            ttile[(c4 + 0) * 65 + r] = v.x;
            ttile[(c4 + 1) * 65 + r] = v.y;
            ttile[(c4 + 2) * 65 + r] = v.z;
            ttile[(c4 + 3) * 65 + r] = v.w;
        }
        __syncthreads();
        const int rr = tid >> 2, cc = (tid & 3) * 16;
        const int n  = n0 + rr;
        short8 s0, s1;
        #pragma unroll
        for (int j = 0; j < 8; ++j) {
            s0[j] = (short)__bfloat16_as_ushort(__float2bfloat16(ttile[rr * 65 + cc + j]));
            s1[j] = (short)__bfloat16_as_ushort(__float2bfloat16(ttile[rr * 65 + cc + 8 + j]));
        }
        const int c0  = (k0 + cc) >> 3;
        const int c1  = c0 + 1;
        const int c0s = (c0 & ~7) | ((c0 ^ n) & 7);
        const int c1s = (c1 & ~7) | ((c1 ^ n) & 7);
        *(short8*)(Wdst + (size_t)n * Kdst + c0s * 8) = s0;
        *(short8*)(Wdst + (size_t)n * Kdst + c1s * 8) = s1;
        return;
    }

    if (bid == T_TILES) {
        // ---------------- bias pad branch (1 block) -------------------------
        if (tid < 256) {
            b1p[tid] = (tid < H_N) ? b1[tid] : 0.f;
            b2p[tid] = (tid < H_N) ? b2[tid] : 0.f;
            if (tid + 256 < NP2) {
                b1p[tid + 256] = (tid + 256 < H_N) ? b1[tid + 256] : 0.f;
                b2p[tid + 256] = (tid + 256 < H_N) ? b2[tid + 256] : 0.f;
            }
        }
        return;
    }

    // ----- gather branch: 4 rows, 1 wave per row, register-only FM ----------
    const int gb   = bid - (T_TILES + 1);
    const int r    = tid >> 6;                // wave id 0..3
    const int l    = tid & 63;
    // XCD-aligned row mapping: XCD (gb&7) produces rows 512*(gb&7) ..
    const int grow = (gb & 7) * 512 + (gb >> 3) * 4 + r;
    const int base = grow * F_N;

    int   idxv[4];
    float valv[4];
    #pragma unroll
    for (int it = 0; it < 4; ++it) {
        const int t  = l + it * 64;
        const int fi = (t < 156) ? (t >> 2) : ((t < 156 + F_N) ? (t - 156) : 0);
        idxv[it] = Xi[base + fi];
        valv[it] = Xv[base + fi];
    }

    float4 gv[4];
    float  fv[4];
    #pragma unroll
    for (int it = 0; it < 4; ++it) {
        const int t = l + it * 64;
        gv[it] = make_float4(0.f, 0.f, 0.f, 0.f);
        fv[it] = 0.f;
        if (t < 156) {
            gv[it] = *(const float4*)(sec_t +
                     ((long long)(t >> 2) * V_N + idxv[it]) * D_N + (t & 3) * 4);
        } else if (t < 156 + F_N) {
            fv[it] = fst_t[(long long)(t - 156) * V_N + idxv[it]];
        }
    }

    float4 vsum = make_float4(0.f, 0.f, 0.f, 0.f);  // colsum partial (d-class l&3)
    float  ssq = 0.f, fstp = 0.f;
    #pragma unroll
    for (int it = 0; it < 4; ++it) {
        const int t = l + it * 64;
        if (t < 160) {
            float4 v = make_float4(0.f, 0.f, 0.f, 0.f);
            if (t < 156) {
                const float val = valv[it];
                v.x = gv[it].x * val; v.y = gv[it].y * val;
                v.z = gv[it].z * val; v.w = gv[it].w * val;
                ssq += v.x * v.x + v.y * v.y + v.z * v.z + v.w * v.w;
                vsum.x += v.x; vsum.y += v.y; vsum.z += v.z; vsum.w += v.w;
            }
            ushort4 pk;
            pk.x = __bfloat16_as_ushort(__float2bfloat16(v.x));
            pk.y = __bfloat16_as_ushort(__float2bfloat16(v.y));
            pk.z = __bfloat16_as_ushort(__float2bfloat16(v.z));
            pk.w = __bfloat16_as_ushort(__float2bfloat16(v.w));
            const int ch = t >> 1;                       // 16B chunk
            const int cs = (ch & ~7) | ((ch ^ grow) & 7);
            *(ushort4*)(sec_flat + (size_t)grow * K1P + cs * 8 + (t & 1) * 4) = pk;
        }
        if (t >= 156 && t < 156 + F_N)
            fstp += fv[it] * valv[it];
    }

    // colsum over features: reduce within d-class (lanes l, l+4, ..., l+60)
    #pragma unroll
    for (int off = 4; off < 64; off <<= 1) {
        vsum.x += __shfl_xor(vsum.x, off, 64);
        vsum.y += __shfl_xor(vsum.y, off, 64);
        vsum.z += __shfl_xor(vsum.z, off, 64);
        vsum.w += __shfl_xor(vsum.w, off, 64);
    }
    float s2 = vsum.x * vsum.x + vsum.y * vsum.y + vsum.z * vsum.z + vsum.w * vsum.w;
    s2 += __shfl_xor(s2, 1, 64);
    s2 += __shfl_xor(s2, 2, 64);
    float rsc = fstp - 0.5f * ssq;
    #pragma unroll
    for (int off = 1; off < 64; off <<= 1)
        rsc += __shfl_xor(rsc, off, 64);
    if (l == 0) out[grow] = rsc + 0.5f * s2 + bias[0];
}

// ---- kernel 2/3: bf16 MFMA GEMM, 64x64 tile, 3-buf counted-vmcnt (r12) -----
template <int KT, bool ROWSUM>
__global__ __launch_bounds__(256) void mfma_gemm(
    const __hip_bfloat16* __restrict__ A,
    const __hip_bfloat16* __restrict__ Bt,
    const float* __restrict__ bias,
    __hip_bfloat16* __restrict__ C,
    float* __restrict__ out)
{
    __shared__ __align__(16) __hip_bfloat16 As[3][64 * 64];  // 24 KB
    __shared__ __align__(16) __hip_bfloat16 Bs[3][64 * 64];  // 24 KB

    const int tid  = threadIdx.x;
    const int lane = tid & 63;
    const int wid  = tid >> 6;       // 4 waves: 2 (M) x 2 (N)
    const int wm   = wid >> 1;
    const int wn   = wid & 1;
    const int lr   = lane & 15;
    const int lg4  = lane >> 4;

    // XCD-chunked swizzle: XCD x gets tiles 56x..56x+55 = row panels 8x..8x+7
    const int lin  = blockIdx.x;
    const int swz  = (lin & 7) * 56 + (lin >> 3);
    const int row0 = (swz / 7) * 64;
    const int col0 = (swz % 7) * 64;

    const int sr = tid >> 3;         // staging row 0..31
    const int sc = (tid & 7) * 8;    // 16B chunk

    float bvv[2];
    #pragma unroll
    for (int n = 0; n < 2; ++n)
        bvv[n] = bias[col0 + wn * 32 + n * 16 + lr];
    asm volatile("" :: "v"(bvv[0]), "v"(bvv[1]));
    asm volatile("s_waitcnt vmcnt(0)" ::: "memory");

    auto STAGE = [&](int buf, int k0) {   // 4 gload_lds per thread
        #pragma unroll
        for (int i = 0; i < 2; ++i) {
            __builtin_amdgcn_global_load_lds(
                (g_void*)(A + (size_t)(row0 + i * 32 + sr) * KT + k0 + sc),
                (l_void*)(&As[buf][(i * 32 + sr) * 64 + sc]), 16, 0, 0);
            __builtin_amdgcn_global_load_lds(
                (g_void*)(Bt + (size_t)(col0 + i * 32 + sr) * KT + k0 + sc),
                (l_void*)(&Bs[buf][(i * 32 + sr) * 64 + sc]), 16, 0, 0);
        }
    };

    constexpr int NT = KT / 64;
    STAGE(0, 0);
    STAGE(1, 64);

    f32x4 acc[2][2] = {};
    for (int t = 0; t < NT; ++t) {
        if (t + 1 < NT) asm volatile("s_waitcnt vmcnt(4)" ::: "memory");
        else            asm volatile("s_waitcnt vmcnt(0)" ::: "memory");
        __builtin_amdgcn_s_barrier();
        if (t + 2 < NT) STAGE((t + 2) % 3, (t + 2) * 64);

        const int cb = t % 3;
        #pragma unroll
        for (int ks = 0; ks < 2; ++ks) {
            short8 a[2], bb[2];
            #pragma unroll
            for (int m = 0; m < 2; ++m) {
                const int row = wm * 32 + m * 16 + lr;
                const int ch  = (ks * 4 + lg4) ^ (row & 7);
                a[m] = *(const short8*)(&As[cb][row * 64 + ch * 8]);
            }
            #pragma unroll
            for (int n = 0; n < 2; ++n) {
                const int row = wn * 32 + n * 16 + lr;
                const int ch  = (ks * 4 + lg4) ^ (row & 7);
                bb[n] = *(const short8*)(&Bs[cb][row * 64 + ch * 8]);
            }
            #pragma unroll
            for (int m = 0; m < 2; ++m)
                #pragma unroll
                for (int n = 0; n < 2; ++n)
                    acc[m][n] = __builtin_amdgcn_mfma_f32_16x16x32_bf16(
                        a[m], bb[n], acc[m][n], 0, 0, 0);
        }
    }

    // epilogue — C/D layout: col = lane&15, row = (lane>>4)*4 + reg  [m89]
    if constexpr (!ROWSUM) {
        __syncthreads();
        float* ctile = (float*)&As[0][0];      // 64x64 f32 = 16 KB
        #pragma unroll
        for (int m = 0; m < 2; ++m) {
            const int rb = wm * 32 + m * 16 + lg4 * 4;
            #pragma unroll
            for (int n = 0; n < 2; ++n) {
                const int col = wn * 32 + n * 16 + lr;
                #pragma unroll
                for (int r = 0; r < 4; ++r)
                    ctile[(rb + r) * 64 + col] = fmaxf(acc[m][n][r] + bvv[n], 0.f);
            }
        }
        __syncthreads();
        const int row = tid >> 2;              // 0..63
        const int cc  = (tid & 3) * 16;
        short8 s0, s1;
        #pragma unroll
        for (int j = 0; j < 8; ++j) {
            s0[j] = (short)__bfloat16_as_ushort(__float2bfloat16(ctile[row * 64 + cc + j]));
            s1[j] = (short)__bfloat16_as_ushort(__float2bfloat16(ctile[row * 64 + cc + 8 + j]));
        }
        const int c0  = (col0 + cc) >> 3;
        const int c1  = c0 + 1;
        const int c0s = (c0 & ~7) | ((c0 ^ row) & 7);
        const int c1s = (c1 & ~7) | ((c1 ^ row) & 7);
        *(short8*)(C + (size_t)(row0 + row) * NP2 + c0s * 8) = s0;
        *(short8*)(C + (size_t)(row0 + row) * NP2 + c1s * 8) = s1;
    } else {
        #pragma unroll
        for (int m = 0; m < 2; ++m) {
            float v[4] = {0.f, 0.f, 0.f, 0.f};
            #pragma unroll
            for (int n = 0; n < 2; ++n) {
                #pragma unroll
                for (int r = 0; r < 4; ++r)
                    v[r] += fmaxf(acc[m][n][r] + bvv[n], 0.f);
            }
            #pragma unroll
            for (int off = 1; off < 16; off <<= 1)
                #pragma unroll
                for (int r = 0; r < 4; ++r)
                    v[r] += __shfl_xor(v[r], off, 64);
            if (lr == 0) {
                const int row = row0 + wm * 32 + m * 16 + lg4 * 4;
                #pragma unroll
                for (int r = 0; r < 4; ++r)
                    atomicAdd(out + row + r, v[r]);
            }
        }
    }
}

extern "C" void kernel_launch(void* const* d_in, const int* in_sizes, int n_in,
                              void* d_out, int out_size, void* d_ws, size_t ws_size,
                              hipStream_t stream)
{
    const int*   Xi    = (const int*)  d_in[0];
    const float* Xv    = (const float*)d_in[1];
    const float* fst_t = (const float*)d_in[2];
    const float* sec_t = (const float*)d_in[3];
    const float* W1    = (const float*)d_in[4];
    const float* b1    = (const float*)d_in[5];
    const float* W2    = (const float*)d_in[6];
    const float* b2    = (const float*)d_in[7];
    const float* bias  = (const float*)d_in[8];

    float* out = (float*)d_out;
    char*  wsb = (char*)d_ws;

    __hip_bfloat16* sec_flat = (__hip_bfloat16*)(wsb);                // 4096*640*2
    __hip_bfloat16* h        = (__hip_bfloat16*)(wsb + 5242880);      // 4096*448*2
    __hip_bfloat16* W1t      = (__hip_bfloat16*)(wsb + 8912896);      // 448*640*2
    __hip_bfloat16* W2t      = (__hip_bfloat16*)(wsb + 9486336);      // 448*448*2
    float*          b1p      = (float*)(wsb + 9887744);               // 448*4
    float*          b2p      = (float*)(wsb + 9889536);               // 448*4

    prep_kernel<<<PREP_GRID, 256, 0, stream>>>(
        Xi, Xv, fst_t, sec_t, bias, W1, b1, W2, b2,
        sec_flat, W1t, W2t, b1p, b2p, out);

    mfma_gemm<K1P, false><<<448, 256, 0, stream>>>(sec_flat, W1t, b1p, h, nullptr);
    mfma_gemm<NP2, true ><<<448, 256, 0, stream>>>(h, W2t, b2p, nullptr, out);
}